// Round 7
// baseline (34675.165 us; speedup 1.0000x reference)
//
#include <hip/hip_runtime.h>
#include <stdint.h>

// MUCMA — round 7: two-wave producer/consumer split, conflict-free LDS exchange.
//   wave A (chain): v(n) = Araw(n) - c'(n-1)S1(n-1) - c'(n-2)S2(n-2) - c'(n-3)S3(n-3);
//                   z/r/q/c' recurrence; publishes c'(n) to LDS; stores v(n).
//   wave B (tree):  maintains w lagged 3; Araw(m+2) = <w(m-1), u(m+2)> -> LDS.
//   Sk(n) = <conj u(n), u(n+k)> precomputed in parallel (gram3_kernel -> d_ws).
// Round-7 change: all cross-wave LDS writes and the v store are exec-masked to
// the 2 owner lanes (sl==0 per half) instead of dummy-slot writes — round 6's
// dummy addressing was a 62-way bank-0 conflict (1.5e7 SQ_LDS_BANK_CONFLICT,
// ~118 cyc/step on the critical path).
// Sync: one raw {lgkmcnt(0); s_barrier} per step — vmcnt NOT drained.

typedef float v2f __attribute__((ext_vector_type(2)));
typedef float v4f __attribute__((ext_vector_type(4), aligned(8)));

constexpr int   NTAPS   = 19;
constexpr int   FRST    = 38;
constexpr float BETA_C  = 0.999f;
constexpr float OMB_C   = 0.001f;
constexpr float LR_C    = 0.0001220703125f;   // 2^-13
constexpr float R2_C    = 1.32f;
constexpr int   SPLIT_N = 24576;              // beta^(n+1) == 0 in f32 beyond here

template <int CTRL>
__device__ __forceinline__ float dpp_add(float x) {
    return x + __int_as_float(__builtin_amdgcn_update_dpp(
        0, __float_as_int(x), CTRL, 0xF, 0xF, true));
}
template <int CTRL>
__device__ __forceinline__ float dpp_mov(float x) {
    return __int_as_float(__builtin_amdgcn_update_dpp(
        0, __float_as_int(x), CTRL, 0xF, 0xF, true));
}
// 4-stage rotation butterfly: every lane of each 16-lane row gets the row total.
__device__ __forceinline__ float rowred_bcast(float x) {
    x = dpp_add<0x121>(x);
    x = dpp_add<0x122>(x);
    x = dpp_add<0x124>(x);
    x = dpp_add<0x128>(x);
    return x;
}
__device__ __forceinline__ void plane32_swap(float& a, float& b) {
    asm("s_nop 1\n\t"
        "v_permlane32_swap_b32 %0, %1\n\t"
        "s_nop 1"
        : "+v"(a), "+v"(b));
}
__device__ __forceinline__ void plane32_swap2(float& a, float& b, float& c, float& d) {
    asm("s_nop 1\n\t"
        "v_permlane32_swap_b32 %0, %1\n\t"
        "v_permlane32_swap_b32 %2, %3\n\t"
        "s_nop 1"
        : "+v"(a), "+v"(b), "+v"(c), "+v"(d));
}
__device__ __forceinline__ void wg_barrier() {
    asm volatile("s_waitcnt lgkmcnt(0)\n\ts_barrier" ::: "memory");
}

// ---------- parallel precompute: Sk(n) = <conj u(n), u(n+k)>, k=1..3 ----------
__global__ void __launch_bounds__(64)
gram3_kernel(const float* __restrict__ fr_re, const float* __restrict__ fr_im,
             char* __restrict__ ws, int nsym)
{
    v4f* SA4 = (v4f*)ws;                              // {S1r,S1i,S2r,S2i}
    v2f* SA2 = (v2f*)(ws + (size_t)nsym * 16);        // {S3r,S3i}
    __shared__ float lre[67 * FRST], lim[67 * FRST];
    const int lane = threadIdx.x;
    const int n0   = blockIdx.x * 64;
    const long gmax = (long)nsym * FRST;
    for (int idx = lane; idx < 67 * FRST; idx += 64) {
        const long g = (long)n0 * FRST + idx;
        if (g < gmax) { lre[idx] = fr_re[g]; lim[idx] = fr_im[g]; }
    }
    __syncthreads();
    const int n = n0 + lane;
    if (n >= nsym) return;
    const float* ar = lre + lane * FRST;
    const float* ai = lim + lane * FRST;
    v2f s1 = {0.f,0.f}, s2 = {0.f,0.f}, s3 = {0.f,0.f};
#pragma unroll
    for (int e = 0; e < FRST; ++e) {
        const float xr = ar[e], xi = ai[e];
        const float b1r = ar[e+FRST],   b1i = ai[e+FRST];
        const float b2r = ar[e+2*FRST], b2i = ai[e+2*FRST];
        const float b3r = ar[e+3*FRST], b3i = ai[e+3*FRST];
        s1.x += xr*b1r + xi*b1i;  s1.y += xr*b1i - xi*b1r;
        s2.x += xr*b2r + xi*b2i;  s2.y += xr*b2i - xi*b2r;
        s3.x += xr*b3r + xi*b3i;  s3.y += xr*b3i - xi*b3r;
    }
    if (n + 1 >= nsym) s1 = (v2f){0.f,0.f};
    if (n + 2 >= nsym) s2 = (v2f){0.f,0.f};
    if (n + 3 >= nsym) s3 = (v2f){0.f,0.f};
    SA4[n] = (v4f){s1.x, s1.y, s2.x, s2.y};
    SA2[n] = s3;
}

// ---------- wave A state / step ----------
struct AS {
    float araw_r, araw_i;
    float cp1r, cp1i, cp2r, cp2i, cp3r, cp3i;
    float z_re, z_im, r_re, r_im, bp;
    v4f sa4[8]; v2f sa2[8];
    const v4f* pa40; const v2f* pa20;   // bases (for tail clamping)
    const v4f* pa4;  const v2f* pa2;    // advancing per-block bases
    float* stb;                         // out + 2h, advances 32 floats/block
    bool stf;
};

template <bool EARLY, int P>
__device__ __forceinline__ void A_step(AS& s, const v4f* p4, const v2f* p2,
                                       bool ok, float* cw, const float* ard,
                                       bool d0f, bool csel)
{
    const v4f S1e = s.sa4[(P+7)&7];
    const v4f S2e = s.sa4[(P+6)&7];
    const v2f S3e = s.sa2[(P+5)&7];

    float vr = s.araw_r - (s.cp1r*S1e.x - s.cp1i*S1e.y)
                        - (s.cp2r*S2e.z - s.cp2i*S2e.w)
                        - (s.cp3r*S3e.x - s.cp3i*S3e.y);
    float vi = s.araw_i - (s.cp1r*S1e.y + s.cp1i*S1e.x)
                        - (s.cp2r*S2e.w + s.cp2i*S2e.z)
                        - (s.cp3r*S3e.y + s.cp3i*S3e.x);

    const v2f an = *(const v2f*)(ard + ((P+1)&7)*4);   // prefetch Araw(n+1) (broadcast read)

    if (s.stf && ok)                                   // emit v(n): 2 active lanes
        *(v2f*)(s.stb + P*4) = (v2f){vr, vi};

    float Xr = vr, Yr = vr, Xi = vi, Yi = vi;
    plane32_swap2(Xr, Yr, Xi, Yi);
    const float vlr = csel ? Xr : Yr;
    const float vli = csel ? Xi : Yi;

    const float zsr = dpp_mov<0x111>(s.z_re);
    const float zsi = dpp_mov<0x111>(s.z_im);
    s.z_re = d0f ? vlr : zsr;
    s.z_im = d0f ? vli : zsi;

    const float ar = OMB_C * vr, ai = OMB_C * vi;
    s.r_re = BETA_C * s.r_re + (ar * s.z_re + ai * s.z_im);
    s.r_im = BETA_C * s.r_im + (ai * s.z_re - ar * s.z_im);

    float qr = s.r_re * s.z_re + s.r_im * s.z_im;
    float qi = s.r_im * s.z_re - s.r_re * s.z_im;
    qr = rowred_bcast(qr);
    qi = rowred_bcast(qi);

    float i2;
    if (EARLY) {
        const float inv = __builtin_amdgcn_rcpf(1.0f - s.bp);
        s.bp *= BETA_C;
        i2 = (2.0f * LR_C) * inv;
    } else {
        i2 = 2.0f * LR_C;
    }
    const float t  = vr*vr + vi*vi;
    const float e2 = fmaf(2.0f*LR_C, t, -(2.0f*LR_C)*R2_C);
    const float cr = fmaf(e2, vr, i2*qr);
    const float ci = fmaf(e2, vi, i2*qi);

    if (s.stf)                                          // publish c'(n): 2 active lanes
        *(v2f*)(cw + P*4) = (v2f){cr, ci};

    s.cp3r = s.cp2r; s.cp3i = s.cp2i;
    s.cp2r = s.cp1r; s.cp2i = s.cp1i;
    s.cp1r = cr;     s.cp1i = ci;
    s.araw_r = an.x; s.araw_i = an.y;

    s.sa4[(P+5)&7] = p4[0];                             // S-ring refill (uniform addr)
    s.sa2[(P+5)&7] = p2[0];
}

template <bool EARLY, bool TAIL>
__device__ __forceinline__ void a_block(AS& s, int nb, int last,
    float* cw, const float* ard, bool d0f, bool csel)
{
#define ASTP(P) { \
    const v4f* p4; const v2f* p2; bool ok = true; \
    if (TAIL) { int rfi = nb + P + 5; if (rfi > last) rfi = last; \
                p4 = s.pa40 + rfi; p2 = s.pa20 + rfi; ok = (nb + P <= last); } \
    else { p4 = s.pa4 + (P+5); p2 = s.pa2 + (P+5); } \
    A_step<EARLY, P>(s, p4, p2, ok, cw, ard, d0f, csel); \
    wg_barrier(); }
    ASTP(0) ASTP(1) ASTP(2) ASTP(3) ASTP(4) ASTP(5) ASTP(6) ASTP(7)
#undef ASTP
    s.pa4 += 8; s.pa2 += 8; s.stb += 32;
}

// ---------- wave B state / step ----------
struct BS {
    v2f wA_r, wA_i, wB_r, wB_i;
    v4f rr[8], ri[8];
    v4f uo_r, uo_i;               // u(m-2)
    float cregr, cregi;           // c'(m-2)
    const float* ubr; const float* ubi;
    float mA, mB;
    bool stf;
};

__device__ __forceinline__ v2f b_tree(const BS& s, const v4f& uR, const v4f& uI) {
    const v2f uA_r = {uR.x,uR.y}, uB_r = {uR.z,uR.w};
    const v2f uA_i = {uI.x,uI.y}, uB_i = {uI.z,uI.w};
    v2f tr = s.wA_r*uA_r - s.wA_i*uA_i + s.wB_r*uB_r - s.wB_i*uB_i;
    v2f ti = s.wA_r*uA_i + s.wA_i*uA_r + s.wB_r*uB_i + s.wB_i*uB_r;
    return (v2f){ rowred_bcast(tr.x + tr.y), rowred_bcast(ti.x + ti.y) };
}

template <int P>
__device__ __forceinline__ void B_step(BS& s, const float* urf_re, const float* urf_im,
                                       const float* crd, float* aw)
{
    const v2f cn = *(const v2f*)(crd + ((P+7)&7)*4);    // c'(m-1) (broadcast read)

    // w(m-2) -> w(m-1) with c'(m-2), conj(u(m-2))
    const float crA = s.cregr * s.mA, ciA = s.cregi * s.mA;
    const float crB = s.cregr * s.mB, ciB = s.cregi * s.mB;
    {
        const v2f uA_r = {s.uo_r.x, s.uo_r.y}, uB_r = {s.uo_r.z, s.uo_r.w};
        const v2f uA_i = {s.uo_i.x, s.uo_i.y}, uB_i = {s.uo_i.z, s.uo_i.w};
        s.wA_r -= (v2f){crA,crA}*uA_r + (v2f){ciA,ciA}*uA_i;
        s.wA_i -= (v2f){ciA,ciA}*uA_r - (v2f){crA,crA}*uA_i;
        s.wB_r -= (v2f){crB,crB}*uB_r + (v2f){ciB,ciB}*uB_i;
        s.wB_i -= (v2f){ciB,ciB}*uB_r - (v2f){crB,crB}*uB_i;
    }
    // Araw(m+2) = <w(m-1), u(m+2)>
    {
        const v2f T = b_tree(s, s.rr[(P+2)&7], s.ri[(P+2)&7]);
        if (s.stf)                                      // 2 active lanes, conflict-free
            *(v2f*)(aw + ((P+2)&7)*4) = T;
    }
    s.uo_r = s.rr[(P+7)&7];
    s.uo_i = s.ri[(P+7)&7];
    s.rr[(P+7)&7] = *(const v4f*)urf_re;                // u(m+7) refill
    s.ri[(P+7)&7] = *(const v4f*)urf_im;
    s.cregr = cn.x; s.cregi = cn.y;
}

template <bool TAIL>
__device__ __forceinline__ void b_block(BS& s, int nb, int last,
    const float* fr_re, const float* fr_im, int loff,
    const float* crd, float* aw)
{
#define BSTP(P) { \
    const float* ur; const float* ui2; \
    if (TAIL) { int rfi = nb + P + 7; if (rfi > last) rfi = last; \
                ur  = fr_re + (size_t)rfi * FRST + loff; \
                ui2 = fr_im + (size_t)rfi * FRST + loff; } \
    else { ur = s.ubr + P*FRST; ui2 = s.ubi + P*FRST; } \
    B_step<P>(s, ur, ui2, crd, aw); \
    wg_barrier(); }
    BSTP(0) BSTP(1) BSTP(2) BSTP(3) BSTP(4) BSTP(5) BSTP(6) BSTP(7)
#undef BSTP
    s.ubr += 8*FRST; s.ubi += 8*FRST;
}

// ---------- 2-wave scan kernel ----------
__global__ void __launch_bounds__(128, 1)
mucma2_kernel(const float* __restrict__ fr_re, const float* __restrict__ fr_im,
              const float* __restrict__ w0r_in, const float* __restrict__ w0i_in,
              char* __restrict__ ws, float* __restrict__ out, int nsym)
{
    __shared__ __align__(16) float cring[8][2][2];
    __shared__ __align__(16) float aring[8][2][2];

    const int  tid  = threadIdx.x;
    const int  wid  = tid >> 6;
    const int  lane = tid & 63;
    const int  sl   = lane & 31;
    const int  h    = lane >> 5;
    const int  loff = (4*sl < 34) ? 4*sl : 34;
    const bool d0f  = (sl == 10);
    const bool stf  = (sl == 0);
    const int  last = nsym - 1;

    bool csel;
    { const float own = h ? 11.f : 7.f; float v = own, X = own;
      plane32_swap(X, v); csel = (X != own); }

    int NBm = (nsym - 14) / 8; if (NBm < 0) NBm = 0;
    const int nmain = NBm * 8;
    const int ne    = (SPLIT_N < nmain) ? SPLIT_N : nmain;

    if (wid == 0) {
        // ================= wave A (chain) =================
        if (lane < 32) ((float*)cring)[lane] = 0.f;     // distinct banks
        else           ((float*)aring)[lane - 32] = 0.f;
        wg_barrier();                                   // #1
        wg_barrier();                                   // #2 (B wrote Araw(0),Araw(1))

        AS s;
        uintptr_t a4u = (uintptr_t)ws;                     asm volatile("" : "+v"(a4u));
        uintptr_t a2u = (uintptr_t)(ws + (size_t)nsym*16); asm volatile("" : "+v"(a2u));
        s.pa40 = (const v4f*)a4u; s.pa20 = (const v2f*)a2u;
        s.pa4 = s.pa40; s.pa2 = s.pa20;
#pragma unroll
        for (int k = 0; k < 8; ++k) {
            const int idx = (k < 5) ? ((k <= last) ? k : last) : 0;
            s.sa4[k] = s.pa40[idx];
            s.sa2[k] = s.pa20[idx];
        }
        s.stb = out + 2*h;
        s.stf = stf;
        s.cp1r=0.f; s.cp1i=0.f; s.cp2r=0.f; s.cp2i=0.f; s.cp3r=0.f; s.cp3i=0.f;
        s.z_re=0.f; s.z_im=0.f; s.r_re=0.f; s.r_im=0.f; s.bp = BETA_C;
        { const v2f a0 = *(const v2f*)&aring[0][h][0]; s.araw_r = a0.x; s.araw_i = a0.y; }
        float* cw = &cring[0][h][0];
        const float* ard = &aring[0][h][0];

        for (int nb = 0;  nb < ne;    nb += 8) a_block<true , false>(s, nb, last, cw, ard, d0f, csel);
        for (int nb = ne; nb < nmain; nb += 8) a_block<false, false>(s, nb, last, cw, ard, d0f, csel);
        if (nmain < SPLIT_N)
            for (int nb = nmain; nb < nsym; nb += 8) a_block<true , true>(s, nb, last, cw, ard, d0f, csel);
        else
            for (int nb = nmain; nb < nsym; nb += 8) a_block<false, true>(s, nb, last, cw, ard, d0f, csel);
    } else {
        // ================= wave B (tree) =================
        BS s;
        s.mA = (sl <= 8) ? 1.f : 0.f;
        s.mB = (sl <= 9) ? 1.f : 0.f;
        s.stf = stf;
        s.wA_r = (v2f){0.f,0.f}; s.wA_i = (v2f){0.f,0.f};
        s.wB_r = (v2f){0.f,0.f}; s.wB_i = (v2f){0.f,0.f};
        if (sl <= 8) {
            const int b = h*FRST + 2*sl;
            s.wA_r.x = w0r_in[b];       s.wA_r.y = w0r_in[b+NTAPS];
            s.wA_i.x = w0i_in[b];       s.wA_i.y = w0i_in[b+NTAPS];
            s.wB_r.x = w0r_in[b+1];     s.wB_r.y = w0r_in[b+NTAPS+1];
            s.wB_i.x = w0i_in[b+1];     s.wB_i.y = w0i_in[b+NTAPS+1];
        } else if (sl == 9) {
            s.wB_r.x = w0r_in[h*FRST+18];  s.wB_r.y = w0r_in[h*FRST+37];
            s.wB_i.x = w0i_in[h*FRST+18];  s.wB_i.y = w0i_in[h*FRST+37];
        }
        const float* pre = fr_re + loff;
        const float* pim = fr_im + loff;
#pragma unroll
        for (int k = 0; k < 7; ++k) {
            const int idx = (k <= last) ? k : last;
            s.rr[k] = *(const v4f*)(pre + (size_t)idx*FRST);
            s.ri[k] = *(const v4f*)(pim + (size_t)idx*FRST);
        }
        s.rr[7] = (v4f){0.f,0.f,0.f,0.f}; s.ri[7] = (v4f){0.f,0.f,0.f,0.f};
        s.uo_r  = (v4f){0.f,0.f,0.f,0.f}; s.uo_i  = (v4f){0.f,0.f,0.f,0.f};
        s.cregr = 0.f; s.cregi = 0.f;
        s.ubr = pre + (size_t)7*FRST;
        s.ubi = pim + (size_t)7*FRST;
        float* aw = &aring[0][h][0];
        const float* crd = &cring[0][h][0];

        wg_barrier();                                   // #1 (rings zeroed)
        {
            const v2f T0 = b_tree(s, s.rr[0], s.ri[0]);
            const v2f T1 = b_tree(s, s.rr[1], s.ri[1]);
            if (stf) {
                *(v2f*)(aw + 0) = T0;                   // Araw(0)
                *(v2f*)(aw + 4) = T1;                   // Araw(1)
            }
        }
        wg_barrier();                                   // #2

        for (int nb = 0;     nb < nmain; nb += 8) b_block<false>(s, nb, last, fr_re, fr_im, loff, crd, aw);
        for (int nb = nmain; nb < nsym;  nb += 8) b_block<true >(s, nb, last, fr_re, fr_im, loff, crd, aw);
    }
}

// ---------- fallback: round-4 single-wave kernel (no workspace needed) ----------
__global__ void __launch_bounds__(64, 1)
mucma_scan_fb(const float* __restrict__ fr_re, const float* __restrict__ fr_im,
              const float* __restrict__ w0r_in, const float* __restrict__ w0i_in,
              float* __restrict__ out, int nsym)
{
    const int  lane = threadIdx.x;
    const int  sl   = lane & 31;
    const int  h    = lane >> 5;
    const int  loff = (4 * sl < 34) ? 4 * sl : 34;
    const float mA  = (sl <= 8) ? 1.f : 0.f;
    const float mB  = (sl <= 9) ? 1.f : 0.f;
    const bool d0f  = (sl == 10);
    const bool stfl = (sl == 0);

    v2f wA_r = {0.f,0.f}, wA_i = {0.f,0.f}, wB_r = {0.f,0.f}, wB_i = {0.f,0.f};
    if (sl <= 8) {
        const int b = h * FRST + 2 * sl;
        wA_r.x = w0r_in[b];         wA_r.y = w0r_in[b + NTAPS];
        wA_i.x = w0i_in[b];         wA_i.y = w0i_in[b + NTAPS];
        wB_r.x = w0r_in[b + 1];     wB_r.y = w0r_in[b + NTAPS + 1];
        wB_i.x = w0i_in[b + 1];     wB_i.y = w0i_in[b + NTAPS + 1];
    } else if (sl == 9) {
        wB_r.x = w0r_in[h * FRST + 18];  wB_r.y = w0r_in[h * FRST + 37];
        wB_i.x = w0i_in[h * FRST + 18];  wB_i.y = w0i_in[h * FRST + 37];
    }
    float r_re = 0.f, r_im = 0.f, z_re = 0.f, z_im = 0.f;
    float bp = BETA_C;

    bool csel;
    {
        const float own = h ? 11.f : 7.f;
        float v = own, X = own;
        plane32_swap(X, v);
        csel = (X != own);
    }

    const float* pre = fr_re + loff;
    const float* pim = fr_im + loff;

    v4f rr[8], ri[8];
#pragma unroll
    for (int p = 0; p < 8; ++p) {
        const int idx = (p < nsym) ? p : (nsym - 1);
        rr[p] = *(const v4f*)(pre + (size_t)idx * FRST);
        ri[p] = *(const v4f*)(pim + (size_t)idx * FRST);
    }

    auto body = [&](int n, int p, int npf) {
        const v4f uR = rr[p], uI = ri[p];
        rr[p] = *(const v4f*)(pre + (size_t)npf * FRST);
        ri[p] = *(const v4f*)(pim + (size_t)npf * FRST);

        const v2f uA_r = {uR.x, uR.y}, uB_r = {uR.z, uR.w};
        const v2f uA_i = {uI.x, uI.y}, uB_i = {uI.z, uI.w};

        v2f tr = wA_r * uA_r - wA_i * uA_i + wB_r * uB_r - wB_i * uB_i;
        v2f ti = wA_r * uA_i + wA_i * uA_r + wB_r * uB_i + wB_i * uB_r;
        float xr = rowred_bcast(tr.x + tr.y);
        float xi = rowred_bcast(ti.x + ti.y);
        const float vkr = xr, vki = xi;

        float Xr = xr, Xi = xi;
        plane32_swap(Xr, xr);
        plane32_swap(Xi, xi);
        const float vlr = csel ? Xr : xr;
        const float vli = csel ? Xi : xi;

        const float zsr = dpp_mov<0x111>(z_re);
        const float zsi = dpp_mov<0x111>(z_im);
        z_re = d0f ? vlr : zsr;
        z_im = d0f ? vli : zsi;

        const float ar = OMB_C * vkr, ai = OMB_C * vki;
        r_re = BETA_C * r_re + (ar * z_re + ai * z_im);
        r_im = BETA_C * r_im + (ai * z_re - ar * z_im);

        float qr = r_re * z_re + r_im * z_im;
        float qi = r_im * z_re - r_re * z_im;
        qr = rowred_bcast(qr);
        qi = rowred_bcast(qi);

        const float inv = __builtin_amdgcn_rcpf(1.0f - bp);
        bp *= BETA_C;
        const float i2 = (2.0f * LR_C) * inv;
        const float ek = R2_C - (vkr * vkr + vki * vki);
        const float e2 = (-2.0f * LR_C) * ek;
        const float cr = e2 * vkr + i2 * qr;
        const float ci = e2 * vki + i2 * qi;

        const float crA = cr * mA, ciA = ci * mA;
        const float crB = cr * mB, ciB = ci * mB;
        wA_r -= (v2f){crA,crA} * uA_r + (v2f){ciA,ciA} * uA_i;
        wA_i -= (v2f){ciA,ciA} * uA_r - (v2f){crA,crA} * uA_i;
        wB_r -= (v2f){crB,crB} * uB_r + (v2f){ciB,ciB} * uB_i;
        wB_i -= (v2f){ciB,ciB} * uB_r - (v2f){crB,crB} * uB_i;

        if (stfl) {
            v2f o; o.x = vkr; o.y = vki;
            *(v2f*)(out + 4 * (size_t)n + 2 * h) = o;
        }
    };

    int NBmain = nsym / 8 - 1;
    if (NBmain < 0) NBmain = 0;
    for (int b = 0; b < NBmain; ++b) {
        const int nb = b * 8;
#pragma unroll
        for (int p = 0; p < 8; ++p) body(nb + p, p, nb + p + 8);
    }
    for (int nb = NBmain * 8; nb < nsym; nb += 8) {
#pragma unroll
        for (int p = 0; p < 8; ++p) {
            const int n = nb + p;
            if (n < nsym) {
                int npf = n + 8;
                if (npf > nsym - 1) npf = nsym - 1;
                body(n, p, npf);
            }
        }
    }
}

extern "C" void kernel_launch(void* const* d_in, const int* in_sizes, int n_in,
                              void* d_out, int out_size, void* d_ws, size_t ws_size,
                              hipStream_t stream)
{
    const float* fr_re = (const float*)d_in[0];
    const float* fr_im = (const float*)d_in[1];
    const float* w0r   = (const float*)d_in[2];
    const float* w0i   = (const float*)d_in[3];
    float* outp = (float*)d_out;
    const int nsym = in_sizes[0] / FRST;

    const size_t need = (size_t)nsym * 24 + 64 * 1024;
    if (ws_size >= need && nsym >= 16) {
        hipLaunchKernelGGL(gram3_kernel, dim3((nsym + 63) / 64), dim3(64), 0, stream,
                           fr_re, fr_im, (char*)d_ws, nsym);
        hipLaunchKernelGGL(mucma2_kernel, dim3(1), dim3(128), 0, stream,
                           fr_re, fr_im, w0r, w0i, (char*)d_ws, outp, nsym);
    } else {
        hipLaunchKernelGGL(mucma_scan_fb, dim3(1), dim3(64), 0, stream,
                           fr_re, fr_im, w0r, w0i, outp, nsym);
    }
}

// Round 8
// 27113.464 us; speedup vs baseline: 1.2789x; 1.2789x over previous
//
#include <hip/hip_runtime.h>
#include <stdint.h>

// MUCMA — round 8: block-pipelined two-wave split, one barrier per 4 symbols.
//   wave A (chain): v(m) = Acor(m) - sum_{k=1..4+t} c'(m-k) * S_k(m-k),  t = m mod 4.
//     z/r/q/c' recurrence; c' history in an 8-slot register ring; publishes c'(m)
//     to LDS (per-lane slots, conflict-free, no exec masks); stores v(m).
//   wave B (tree):  W lagged one block; per sub-block: read c' of block b-1 (LDS
//     broadcast), 4 rank-1 w-updates, 4 trees -> Acor of block b+1 -> LDS.
//   SC[m][k] = <conj u(m-k), u(m)>, k=1..7, precomputed (gram7_kernel -> d_ws,
//   64 B/symbol, v4f-loadable).
// Rings: aring/cring 8 slots; A and B touch disjoint mod-8 halves each sub-block.
// 16-step superblocks keep every ring index compile-time static (rule #20).
// Row-1 of each half duplicates z/r state so ALL 32 lanes hold valid v/c'
// (all-lane same-address stores, no saveexec — round 7's +4ms lesson).
// Fallback (ws too small / odd nsym): round-4 single-wave kernel.

typedef float v2f __attribute__((ext_vector_type(2)));
typedef float v4f __attribute__((ext_vector_type(4), aligned(8)));

constexpr int   NTAPS   = 19;
constexpr int   FRST    = 38;
constexpr float BETA_C  = 0.999f;
constexpr float OMB_C   = 0.001f;
constexpr float LR_C    = 0.0001220703125f;   // 2^-13
constexpr float R2_C    = 1.32f;
constexpr int   SPLIT_N = 24576;              // beta^(n+1) == 0 in f32 beyond; mult of 16

template <int CTRL>
__device__ __forceinline__ float dpp_add(float x) {
    return x + __int_as_float(__builtin_amdgcn_update_dpp(
        0, __float_as_int(x), CTRL, 0xF, 0xF, true));
}
template <int CTRL>
__device__ __forceinline__ float dpp_mov(float x) {
    return __int_as_float(__builtin_amdgcn_update_dpp(
        0, __float_as_int(x), CTRL, 0xF, 0xF, true));
}
__device__ __forceinline__ float rowred_bcast(float x) {
    x = dpp_add<0x121>(x);   // row_ror:1
    x = dpp_add<0x122>(x);   // row_ror:2
    x = dpp_add<0x124>(x);   // row_ror:4
    x = dpp_add<0x128>(x);   // row_ror:8
    return x;
}
__device__ __forceinline__ void plane32_swap(float& a, float& b) {
    asm("s_nop 1\n\t"
        "v_permlane32_swap_b32 %0, %1\n\t"
        "s_nop 1"
        : "+v"(a), "+v"(b));
}
__device__ __forceinline__ void plane32_swap2(float& a, float& b, float& c, float& d) {
    asm("s_nop 1\n\t"
        "v_permlane32_swap_b32 %0, %1\n\t"
        "v_permlane32_swap_b32 %2, %3\n\t"
        "s_nop 1"
        : "+v"(a), "+v"(b), "+v"(c), "+v"(d));
}
__device__ __forceinline__ void wg_barrier() {
    asm volatile("s_waitcnt lgkmcnt(0)\n\ts_barrier" ::: "memory");
}

// ---------- parallel precompute: SC[m][2(k-1)..] = S_k(m-k) = <conj u(m-k), u(m)> ----------
__global__ void __launch_bounds__(64)
gram7_kernel(const float* __restrict__ fr_re, const float* __restrict__ fr_im,
             float* __restrict__ sc, int nsym)
{
    __shared__ float lre[71 * FRST], lim[71 * FRST];
    const int lane = threadIdx.x;
    const int n0   = blockIdx.x * 64;
    const int base = (n0 - 7) * FRST;                 // lds idx 0 <-> symbol n0-7
    const long gmax = (long)nsym * FRST;
    for (int idx = lane; idx < 71 * FRST; idx += 64) {
        const long g = (long)base + idx;
        float a = 0.f, b = 0.f;
        if (g >= 0 && g < gmax) { a = fr_re[g]; b = fr_im[g]; }
        lre[idx] = a; lim[idx] = b;
    }
    __syncthreads();
    const int m = n0 + lane;
    if (m >= nsym) return;
    const float* br = lre + (lane + 7) * FRST;
    const float* bi = lim + (lane + 7) * FRST;
    float out[16];
#pragma unroll
    for (int k = 1; k <= 7; ++k) {
        const float* ar = br - k * FRST;
        const float* ai = bi - k * FRST;
        float sr = 0.f, si = 0.f;
#pragma unroll
        for (int e = 0; e < FRST; ++e) {
            sr = fmaf(ar[e], br[e], fmaf(ai[e], bi[e], sr));
            si = fmaf(-ai[e], br[e], fmaf(ar[e], bi[e], si));
        }
        const bool ok = (m >= k);
        out[2*(k-1)]   = ok ? sr : 0.f;
        out[2*(k-1)+1] = ok ? si : 0.f;
    }
    out[14] = 0.f; out[15] = 0.f;
    float* d = sc + (size_t)m * 16;
#pragma unroll
    for (int j = 0; j < 4; ++j)
        *(v4f*)(d + 4*j) = (v4f){out[4*j], out[4*j+1], out[4*j+2], out[4*j+3]};
}

// ---------- wave A ----------
struct A_St {
    float acr[8], aci[8];       // Acor ring (static idx)
    float histr[8], histi[8];   // c' history ring
    v4f   scr[4][4];            // SC prefetch ring: scr[m&3][0..3]
    float z_re, z_im, r_re, r_im, bp;
};
struct A_Ctx {
    const float* scp; float* outp;
    float (*aring)[2][32][2]; float (*cring)[2][32][2];
    int h, sl; bool d0f, csel; int last;
};

template <int S, bool EARLY, bool TAIL>
__device__ __forceinline__ void a_pos(A_St& st, const A_Ctx& c, int SB)
{
    constexpr int s8 = S & 7, s4 = S & 3, NC = 4 + (S & 3);
    const int m = SB + S;

    // ---- v(m) = Acor(m) - sum_k c'(m-k) * S_k(m-k) ----
    float vr = st.acr[s8], vi = st.aci[s8];
#pragma unroll
    for (int k = 1; k <= NC; ++k) {
        const float hr = st.histr[(S - k) & 7];
        const float hi = st.histi[(S - k) & 7];
        const v4f sv = st.scr[s4][(k - 1) >> 1];
        const float Sr = (k & 1) ? sv.x : sv.z;
        const float Si = (k & 1) ? sv.y : sv.w;
        vr = fmaf(-hr, Sr, fmaf( hi, Si, vr));
        vi = fmaf(-hr, Si, fmaf(-hi, Sr, vi));
    }

    // emit v(m): all 32 lanes of the half carry identical data -> same-addr store
    *(v2f*)(c.outp + 4 * (size_t)m + 2 * c.h) = (v2f){vr, vi};

    // cross-half v
    float Xr = vr, Yr = vr, Xi = vi, Yi = vi;
    plane32_swap2(Xr, Yr, Xi, Yi);
    const float vlr = c.csel ? Xr : Yr;
    const float vli = c.csel ? Xi : Yi;

    // z shift / insert (both 16-rows of the half keep a valid copy)
    const float zsr = dpp_mov<0x111>(st.z_re);
    const float zsi = dpp_mov<0x111>(st.z_im);
    st.z_re = c.d0f ? vlr : zsr;
    st.z_im = c.d0f ? vli : zsi;

    // r = beta*r + (1-beta)*v_k*conj(z)
    const float ar = OMB_C * vr, ai = OMB_C * vi;
    st.r_re = BETA_C * st.r_re + (ar * st.z_re + ai * st.z_im);
    st.r_im = BETA_C * st.r_im + (ai * st.z_re - ar * st.z_im);

    // mu partials + row-broadcast sum
    float qr = st.r_re * st.z_re + st.r_im * st.z_im;
    float qi = st.r_im * st.z_re - st.r_re * st.z_im;
    qr = rowred_bcast(qr);
    qi = rowred_bcast(qi);

    float i2;
    if (EARLY) {
        const float inv = __builtin_amdgcn_rcpf(1.0f - st.bp);
        st.bp *= BETA_C;
        i2 = (2.0f * LR_C) * inv;
    } else {
        i2 = 2.0f * LR_C;
    }
    const float t  = vr * vr + vi * vi;
    const float e2 = fmaf(2.0f * LR_C, t, -(2.0f * LR_C) * R2_C);
    const float cr = fmaf(e2, vr, i2 * qr);
    const float ci = fmaf(e2, vi, i2 * qi);

    st.histr[s8] = cr; st.histi[s8] = ci;
    // publish c'(m): per-lane slots, 8B stride = 2-way bank aliasing = free
    *(v2f*)&c.cring[s8][c.h][c.sl][0] = (v2f){cr, ci};

    // SC prefetch for m+4 into the slot just consumed
    int mp = m + 4;
    if (TAIL) { if (mp > c.last) mp = c.last; }
    const float* p = c.scp + (size_t)mp * 16;
#pragma unroll
    for (int j = 0; j < 4; ++j)
        st.scr[s4][j] = *(const v4f*)(p + 4 * j);
}

template <int I, bool EARLY, bool TAIL>
__device__ __forceinline__ void a_sub(A_St& st, const A_Ctx& c, int SB)
{
    // Acor reads for this block (published by B one barrier ago; broadcast reads)
#pragma unroll
    for (int t = 0; t < 4; ++t) {
        const v2f a0 = *(const v2f*)&c.aring[(4*I + t) & 7][c.h][0][0];
        st.acr[(4*I + t) & 7] = a0.x;
        st.aci[(4*I + t) & 7] = a0.y;
    }
    a_pos<4*I + 0, EARLY, TAIL>(st, c, SB);
    a_pos<4*I + 1, EARLY, TAIL>(st, c, SB);
    a_pos<4*I + 2, EARLY, TAIL>(st, c, SB);
    a_pos<4*I + 3, EARLY, TAIL>(st, c, SB);
    wg_barrier();
}
template <bool EARLY, bool TAIL>
__device__ __forceinline__ void a_super(A_St& st, const A_Ctx& c, int SB)
{
    a_sub<0, EARLY, TAIL>(st, c, SB);
    a_sub<1, EARLY, TAIL>(st, c, SB);
    a_sub<2, EARLY, TAIL>(st, c, SB);
    a_sub<3, EARLY, TAIL>(st, c, SB);
}

// ---------- wave B ----------
struct B_St {
    v2f wA_r, wA_i, wB_r, wB_i;
    v4f ur[16], ui[16];
    float mA, mB;
};
struct B_Ctx {
    const float* pre; const float* pim;
    float (*aring)[2][32][2]; float (*cring)[2][32][2];
    int h, sl; int last;
};

__device__ __forceinline__ v2f b_tree(const B_St& s, const v4f& uR, const v4f& uI) {
    const v2f uA_r = {uR.x,uR.y}, uB_r = {uR.z,uR.w};
    const v2f uA_i = {uI.x,uI.y}, uB_i = {uI.z,uI.w};
    v2f tr = s.wA_r*uA_r - s.wA_i*uA_i + s.wB_r*uB_r - s.wB_i*uB_i;
    v2f ti = s.wA_r*uA_i + s.wA_i*uA_r + s.wB_r*uB_i + s.wB_i*uB_r;
    return (v2f){ rowred_bcast(tr.x + tr.y), rowred_bcast(ti.x + ti.y) };
}

template <int I, bool TAIL>
__device__ __forceinline__ void b_sub(B_St& st, const B_Ctx& c, int SB)
{
    // c' of block b-1 (broadcast reads; zeros for block -1 via prologue init)
    float ccr[4], cci[4];
#pragma unroll
    for (int t = 0; t < 4; ++t) {
        const v2f cc = *(const v2f*)&c.cring[(4*I + 4 + t) & 7][c.h][0][0];
        ccr[t] = cc.x; cci[t] = cc.y;
    }
    // 4 rank-1 w-updates (order-independent, additive)
#pragma unroll
    for (int t = 0; t < 4; ++t) {
        const float crA = ccr[t] * st.mA, ciA = cci[t] * st.mA;
        const float crB = ccr[t] * st.mB, ciB = cci[t] * st.mB;
        const v4f uR = st.ur[(4*I + 12 + t) & 15], uI = st.ui[(4*I + 12 + t) & 15];
        const v2f uA_r = {uR.x,uR.y}, uB_r = {uR.z,uR.w};
        const v2f uA_i = {uI.x,uI.y}, uB_i = {uI.z,uI.w};
        st.wA_r -= (v2f){crA,crA}*uA_r + (v2f){ciA,ciA}*uA_i;
        st.wA_i -= (v2f){ciA,ciA}*uA_r - (v2f){crA,crA}*uA_i;
        st.wB_r -= (v2f){crB,crB}*uB_r + (v2f){ciB,ciB}*uB_i;
        st.wB_i -= (v2f){ciB,ciB}*uB_r - (v2f){crB,crB}*uB_i;
    }
    // 4 trees for block b+1 -> Acor ring
#pragma unroll
    for (int t = 0; t < 4; ++t) {
        const v2f T = b_tree(st, st.ur[(4*I + 4 + t) & 15], st.ui[(4*I + 4 + t) & 15]);
        *(v2f*)&c.aring[(4*I + 4 + t) & 7][c.h][c.sl][0] = T;
    }
    // refill u frames SB+4I+8+t (1 sub-block of flight time)
#pragma unroll
    for (int t = 0; t < 4; ++t) {
        int f = SB + 4*I + 8 + t;
        if (TAIL) { if (f > c.last) f = c.last; }
        st.ur[(4*I + 8 + t) & 15] = *(const v4f*)(c.pre + (size_t)f * FRST);
        st.ui[(4*I + 8 + t) & 15] = *(const v4f*)(c.pim + (size_t)f * FRST);
    }
    wg_barrier();
}
template <bool TAIL>
__device__ __forceinline__ void b_super(B_St& st, const B_Ctx& c, int SB)
{
    b_sub<0, TAIL>(st, c, SB);
    b_sub<1, TAIL>(st, c, SB);
    b_sub<2, TAIL>(st, c, SB);
    b_sub<3, TAIL>(st, c, SB);
}

// ---------- 2-wave block-pipelined scan ----------
__global__ void __launch_bounds__(128, 1)
mucma2b_kernel(const float* __restrict__ fr_re, const float* __restrict__ fr_im,
               const float* __restrict__ w0r_in, const float* __restrict__ w0i_in,
               const float* __restrict__ scp, float* __restrict__ outp, int nsym)
{
    __shared__ __align__(16) float cring[8][2][32][2];
    __shared__ __align__(16) float aring[8][2][32][2];

    const int  tid  = threadIdx.x;
    const int  wid  = tid >> 6;
    const int  lane = tid & 63;
    const int  sl   = lane & 31;
    const int  h    = lane >> 5;
    const int  loff = (4*sl < 34) ? 4*sl : 34;
    const int  last = nsym - 1;
    const int  SBend = nsym - 16;

    bool csel;
    { const float own = h ? 11.f : 7.f; float v = own, X = own;
      plane32_swap(X, v); csel = (X != own); }

    if (wid == 0) {
        // ================= wave A (chain) =================
        A_St st; A_Ctx c;
        c.scp = scp; c.outp = outp; c.aring = aring; c.cring = cring;
        c.h = h; c.sl = sl; c.d0f = ((sl & 15) == 10); c.csel = csel; c.last = last;
#pragma unroll
        for (int k = 0; k < 8; ++k) {
            st.histr[k] = 0.f; st.histi[k] = 0.f;
            st.acr[k] = 0.f;  st.aci[k] = 0.f;
        }
        st.z_re = 0.f; st.z_im = 0.f; st.r_re = 0.f; st.r_im = 0.f; st.bp = BETA_C;
#pragma unroll
        for (int s = 0; s < 4; ++s)
#pragma unroll
            for (int j = 0; j < 4; ++j)
                st.scr[s][j] = *(const v4f*)(scp + (size_t)s * 16 + 4 * j);
        // zero cring broadcast entries (c' of block -1 = 0)
        if (lane < 32) cring[lane >> 2][(lane >> 1) & 1][0][lane & 1] = 0.f;
        wg_barrier();

        int SB = 0;
        for (; SB < SPLIT_N; SB += 16) a_super<true , false>(st, c, SB);
        for (; SB < SBend;   SB += 16) a_super<false, false>(st, c, SB);
        a_super<false, true>(st, c, SB);
    } else {
        // ================= wave B (tree) =================
        B_St st; B_Ctx c;
        c.pre = fr_re + loff; c.pim = fr_im + loff;
        c.aring = aring; c.cring = cring; c.h = h; c.sl = sl; c.last = last;
        st.mA = (sl <= 8) ? 1.f : 0.f;
        st.mB = (sl <= 9) ? 1.f : 0.f;
        st.wA_r = (v2f){0.f,0.f}; st.wA_i = (v2f){0.f,0.f};
        st.wB_r = (v2f){0.f,0.f}; st.wB_i = (v2f){0.f,0.f};
        if (sl <= 8) {
            const int b = h*FRST + 2*sl;
            st.wA_r.x = w0r_in[b];       st.wA_r.y = w0r_in[b+NTAPS];
            st.wA_i.x = w0i_in[b];       st.wA_i.y = w0i_in[b+NTAPS];
            st.wB_r.x = w0r_in[b+1];     st.wB_r.y = w0r_in[b+NTAPS+1];
            st.wB_i.x = w0i_in[b+1];     st.wB_i.y = w0i_in[b+NTAPS+1];
        } else if (sl == 9) {
            st.wB_r.x = w0r_in[h*FRST+18];  st.wB_r.y = w0r_in[h*FRST+37];
            st.wB_i.x = w0i_in[h*FRST+18];  st.wB_i.y = w0i_in[h*FRST+37];
        }
#pragma unroll
        for (int k = 0; k < 12; ++k) {
            st.ur[k] = *(const v4f*)(c.pre + (size_t)k * FRST);
            st.ui[k] = *(const v4f*)(c.pim + (size_t)k * FRST);
        }
#pragma unroll
        for (int k = 12; k < 16; ++k) {
            st.ur[k] = (v4f){0.f,0.f,0.f,0.f};
            st.ui[k] = (v4f){0.f,0.f,0.f,0.f};
        }
        // prologue: Acor for block 0 (W = w0)
#pragma unroll
        for (int t = 0; t < 4; ++t) {
            const v2f T = b_tree(st, st.ur[t], st.ui[t]);
            *(v2f*)&aring[t][h][sl][0] = T;
        }
        wg_barrier();

        int SB = 0;
        for (; SB < SBend; SB += 16) b_super<false>(st, c, SB);
        b_super<true>(st, c, SB);
    }
}

// ---------- fallback: round-4 single-wave kernel ----------
__global__ void __launch_bounds__(64, 1)
mucma_scan_fb(const float* __restrict__ fr_re, const float* __restrict__ fr_im,
              const float* __restrict__ w0r_in, const float* __restrict__ w0i_in,
              float* __restrict__ out, int nsym)
{
    const int  lane = threadIdx.x;
    const int  sl   = lane & 31;
    const int  h    = lane >> 5;
    const int  loff = (4 * sl < 34) ? 4 * sl : 34;
    const float mA  = (sl <= 8) ? 1.f : 0.f;
    const float mB  = (sl <= 9) ? 1.f : 0.f;
    const bool d0f  = (sl == 10);
    const bool stfl = (sl == 0);

    v2f wA_r = {0.f,0.f}, wA_i = {0.f,0.f}, wB_r = {0.f,0.f}, wB_i = {0.f,0.f};
    if (sl <= 8) {
        const int b = h * FRST + 2 * sl;
        wA_r.x = w0r_in[b];         wA_r.y = w0r_in[b + NTAPS];
        wA_i.x = w0i_in[b];         wA_i.y = w0i_in[b + NTAPS];
        wB_r.x = w0r_in[b + 1];     wB_r.y = w0r_in[b + NTAPS + 1];
        wB_i.x = w0i_in[b + 1];     wB_i.y = w0i_in[b + NTAPS + 1];
    } else if (sl == 9) {
        wB_r.x = w0r_in[h * FRST + 18];  wB_r.y = w0r_in[h * FRST + 37];
        wB_i.x = w0i_in[h * FRST + 18];  wB_i.y = w0i_in[h * FRST + 37];
    }
    float r_re = 0.f, r_im = 0.f, z_re = 0.f, z_im = 0.f;
    float bp = BETA_C;

    bool csel;
    {
        const float own = h ? 11.f : 7.f;
        float v = own, X = own;
        plane32_swap(X, v);
        csel = (X != own);
    }

    const float* pre = fr_re + loff;
    const float* pim = fr_im + loff;

    v4f rr[8], ri[8];
#pragma unroll
    for (int p = 0; p < 8; ++p) {
        const int idx = (p < nsym) ? p : (nsym - 1);
        rr[p] = *(const v4f*)(pre + (size_t)idx * FRST);
        ri[p] = *(const v4f*)(pim + (size_t)idx * FRST);
    }

    auto body = [&](int n, int p, int npf) {
        const v4f uR = rr[p], uI = ri[p];
        rr[p] = *(const v4f*)(pre + (size_t)npf * FRST);
        ri[p] = *(const v4f*)(pim + (size_t)npf * FRST);

        const v2f uA_r = {uR.x, uR.y}, uB_r = {uR.z, uR.w};
        const v2f uA_i = {uI.x, uI.y}, uB_i = {uI.z, uI.w};

        v2f tr = wA_r * uA_r - wA_i * uA_i + wB_r * uB_r - wB_i * uB_i;
        v2f ti = wA_r * uA_i + wA_i * uA_r + wB_r * uB_i + wB_i * uB_r;
        float xr = rowred_bcast(tr.x + tr.y);
        float xi = rowred_bcast(ti.x + ti.y);
        const float vkr = xr, vki = xi;

        float Xr = xr, Xi = xi;
        plane32_swap(Xr, xr);
        plane32_swap(Xi, xi);
        const float vlr = csel ? Xr : xr;
        const float vli = csel ? Xi : xi;

        const float zsr = dpp_mov<0x111>(z_re);
        const float zsi = dpp_mov<0x111>(z_im);
        z_re = d0f ? vlr : zsr;
        z_im = d0f ? vli : zsi;

        const float ar = OMB_C * vkr, ai = OMB_C * vki;
        r_re = BETA_C * r_re + (ar * z_re + ai * z_im);
        r_im = BETA_C * r_im + (ai * z_re - ar * z_im);

        float qr = r_re * z_re + r_im * z_im;
        float qi = r_im * z_re - r_re * z_im;
        qr = rowred_bcast(qr);
        qi = rowred_bcast(qi);

        const float inv = __builtin_amdgcn_rcpf(1.0f - bp);
        bp *= BETA_C;
        const float i2 = (2.0f * LR_C) * inv;
        const float ek = R2_C - (vkr * vkr + vki * vki);
        const float e2 = (-2.0f * LR_C) * ek;
        const float cr = e2 * vkr + i2 * qr;
        const float ci = e2 * vki + i2 * qi;

        const float crA = cr * mA, ciA = ci * mA;
        const float crB = cr * mB, ciB = ci * mB;
        wA_r -= (v2f){crA,crA} * uA_r + (v2f){ciA,ciA} * uA_i;
        wA_i -= (v2f){ciA,ciA} * uA_r - (v2f){crA,crA} * uA_i;
        wB_r -= (v2f){crB,crB} * uB_r + (v2f){ciB,ciB} * uB_i;
        wB_i -= (v2f){ciB,ciB} * uB_r - (v2f){crB,crB} * uB_i;

        if (stfl) {
            v2f o; o.x = vkr; o.y = vki;
            *(v2f*)(out + 4 * (size_t)n + 2 * h) = o;
        }
    };

    int NBmain = nsym / 8 - 1;
    if (NBmain < 0) NBmain = 0;
    for (int b = 0; b < NBmain; ++b) {
        const int nb = b * 8;
#pragma unroll
        for (int p = 0; p < 8; ++p) body(nb + p, p, nb + p + 8);
    }
    for (int nb = NBmain * 8; nb < nsym; nb += 8) {
#pragma unroll
        for (int p = 0; p < 8; ++p) {
            const int n = nb + p;
            if (n < nsym) {
                int npf = n + 8;
                if (npf > nsym - 1) npf = nsym - 1;
                body(n, p, npf);
            }
        }
    }
}

extern "C" void kernel_launch(void* const* d_in, const int* in_sizes, int n_in,
                              void* d_out, int out_size, void* d_ws, size_t ws_size,
                              hipStream_t stream)
{
    const float* fr_re = (const float*)d_in[0];
    const float* fr_im = (const float*)d_in[1];
    const float* w0r   = (const float*)d_in[2];
    const float* w0i   = (const float*)d_in[3];
    float* outp = (float*)d_out;
    const int nsym = in_sizes[0] / FRST;

    const bool use2 = (nsym % 16 == 0) && (nsym >= SPLIT_N + 16)
                   && (ws_size >= (size_t)nsym * 64);
    if (use2) {
        hipLaunchKernelGGL(gram7_kernel, dim3((nsym + 63) / 64), dim3(64), 0, stream,
                           fr_re, fr_im, (float*)d_ws, nsym);
        hipLaunchKernelGGL(mucma2b_kernel, dim3(1), dim3(128), 0, stream,
                           fr_re, fr_im, w0r, w0i, (const float*)d_ws, outp, nsym);
    } else {
        hipLaunchKernelGGL(mucma_scan_fb, dim3(1), dim3(64), 0, stream,
                           fr_re, fr_im, w0r, w0i, outp, nsym);
    }
}